// Round 3
// baseline (1552.253 us; speedup 1.0000x reference)
//
#include <hip/hip_runtime.h>

// Grouped-expert SwiGLU (fp32 in/out) via bf16x3 split-fp32 MFMA emulation.
// Prolog: gate/up/down pre-split into static bf16 hi/lo planes (3 grid-stride
//         kernels, HBM-bound, removes all weight-split VALU from GEMM loops).
// Stage 1: h = silu(x@G^T) * (x@U^T); x split hi/lo in-register; h stored as
//          two bf16 planes in static __device__ buffers.
// Stage 2: out = h @ D^T; both operands read pre-split planes.
// GEMM structure: 128x128 tile, BK=32, 4 waves (2x2), wave tile 64x64 = 2x2
// frags of v_mfma_f32_32x32x16_bf16 (C/D map verified: col=lane&31,
// row=(j&3)+8*(j>>2)+4*(lane>>5)). Padded LDS stride 40 ushorts (80 B).
// 2-phase pipeline: next K-tile global loads issued before the MFMA phase.
// Dynamic counts: per-block prefix sum of 8 counts + early-exit; counts in
// this problem are all multiples of 128 so clamp paths are cold.

constexpr int DIM    = 2048;
constexpr int HIDDEN = 1024;
constexpr int NE     = 8;
constexpr int TOTAL  = 16384;

constexpr int BM = 128, BN = 128, BK = 32;
constexpr int LDT  = 40;          // padded LDS row stride (bf16 elems): 80 B
constexpr int TILE = 128 * LDT;   // ushorts per LDS tile

typedef __attribute__((ext_vector_type(8)))  short bf16x8;
typedef __attribute__((ext_vector_type(16))) float f32x16;

constexpr size_t W_ELEMS = (size_t)NE * HIDDEN * DIM;  // 16.78M (gate/up/down each)
constexpr size_t H_ELEMS = (size_t)TOTAL * HIDDEN;

// Static device buffers (module-load allocated; no d_ws dependency).
__device__ unsigned short g_g_hi[W_ELEMS], g_g_lo[W_ELEMS];
__device__ unsigned short g_u_hi[W_ELEMS], g_u_lo[W_ELEMS];
__device__ unsigned short g_d_hi[W_ELEMS], g_d_lo[W_ELEMS];
__device__ unsigned short g_h_hi[H_ELEMS], g_h_lo[H_ELEMS];

__device__ __forceinline__ unsigned short bf16_rne(float f) {
  unsigned u = __builtin_bit_cast(unsigned, f);
  u += 0x7FFFu + ((u >> 16) & 1u);
  return (unsigned short)(u >> 16);
}
__device__ __forceinline__ float bf16f(unsigned short s) {
  unsigned u = (unsigned)s << 16;
  return __builtin_bit_cast(float, u);
}
__device__ __forceinline__ void split2(float f, unsigned short& hi, unsigned short& lo) {
  hi = bf16_rne(f);
  lo = bf16_rne(f - bf16f(hi));
}

__device__ __forceinline__ void expert_range(const int* __restrict__ counts, int e,
                                             int& lo, int& nloc) {
  lo = 0; nloc = 0;
#pragma unroll
  for (int i = 0; i < NE; ++i) {
    int c = counts[i];
    if (i < e) lo += c;
    if (i == e) nloc = c;
  }
}

// ---------------- Prolog: fp32 -> bf16 hi/lo planes ----------------
__global__ __launch_bounds__(256)
void split_planes(const float* __restrict__ src, unsigned short* __restrict__ hi,
                  unsigned short* __restrict__ lo, int n4) {
  int i = blockIdx.x * blockDim.x + threadIdx.x;
  const int stride = gridDim.x * blockDim.x;
  for (; i < n4; i += stride) {
    const float4 v = ((const float4*)src)[i];
    ushort4 h4, l4;
    split2(v.x, h4.x, l4.x);
    split2(v.y, h4.y, l4.y);
    split2(v.z, h4.z, l4.z);
    split2(v.w, h4.w, l4.w);
    ((ushort4*)hi)[i] = h4;
    ((ushort4*)lo)[i] = l4;
  }
}

// ---------------- Stage 1: h = silu(x@G^T) * (x@U^T) ----------------
__global__ __launch_bounds__(256, 2)
void moe_s1(const float* __restrict__ x, const int* __restrict__ counts) {
  const int e = blockIdx.z;
  int lo, nloc;
  expert_range(counts, e, lo, nloc);
  const int m0 = blockIdx.x * BM;
  if (m0 >= nloc) return;
  const int n0 = blockIdx.y * BN;

  __shared__ unsigned short sm[6 * TILE];
  unsigned short* const Ah = sm;
  unsigned short* const Al = sm + TILE;
  unsigned short* const Gh = sm + 2 * TILE;
  unsigned short* const Gl = sm + 3 * TILE;
  unsigned short* const Uh = sm + 4 * TILE;
  unsigned short* const Ul = sm + 5 * TILE;

  const int tid  = threadIdx.x;
  const int lane = tid & 63;
  const int w    = tid >> 6;
  const int wm   = w >> 1, wn = w & 1;

  const float* const xa = x + (size_t)lo * DIM;
  const size_t wb = ((size_t)e * HIDDEN + n0) * DIM;
  const unsigned short* const Ghg = g_g_hi + wb;
  const unsigned short* const Glg = g_g_lo + wb;
  const unsigned short* const Uhg = g_u_hi + wb;
  const unsigned short* const Ulg = g_u_lo + wb;

  // x staging geometry (fp32, float4): 4 k-chunks x 32 rows
  const int q4 = (tid & 7) * 4;
  const int r0 = tid >> 3;
  // weight staging geometry (bf16x8): 4 k-chunks x 64 rows
  const int k8 = (tid & 3) * 8;
  const int rw = tid >> 2;

  f32x16 accg[2][2], accu[2][2];
#pragma unroll
  for (int i = 0; i < 2; ++i)
#pragma unroll
    for (int j = 0; j < 2; ++j)
#pragma unroll
      for (int k = 0; k < 16; ++k) { accg[i][j][k] = 0.f; accu[i][j][k] = 0.f; }

  float4 va[4];
  bf16x8 vgh[2], vgl[2], vuh[2], vul[2];

  auto load_tile = [&](int kt) {
    const int kbx = kt * BK + q4;
#pragma unroll
    for (int c = 0; c < 4; ++c) {
      const int r  = (c << 5) + r0;
      const int ra = (m0 + r < nloc) ? (m0 + r) : m0;  // clamp: masked at store
      va[c] = *(const float4*)(xa + (size_t)ra * DIM + kbx);
    }
    const int kbw = kt * BK + k8;
#pragma unroll
    for (int c = 0; c < 2; ++c) {
      const size_t ro = (size_t)((c << 6) + rw) * DIM + kbw;
      vgh[c] = *(const bf16x8*)(Ghg + ro);
      vgl[c] = *(const bf16x8*)(Glg + ro);
      vuh[c] = *(const bf16x8*)(Uhg + ro);
      vul[c] = *(const bf16x8*)(Ulg + ro);
    }
  };

  const int NT = DIM / BK;  // 64
  load_tile(0);

  for (int kt = 0; kt < NT; ++kt) {
    __syncthreads();  // all waves done reading previous LDS tile
    // x: split hi/lo in-register, write both planes
#pragma unroll
    for (int c = 0; c < 4; ++c) {
      ushort4 hh, ll;
      split2(va[c].x, hh.x, ll.x);
      split2(va[c].y, hh.y, ll.y);
      split2(va[c].z, hh.z, ll.z);
      split2(va[c].w, hh.w, ll.w);
      const int o = ((c << 5) + r0) * LDT + q4;
      *(ushort4*)(Ah + o) = hh;
      *(ushort4*)(Al + o) = ll;
    }
    // weights: direct plane writes (no conversion)
#pragma unroll
    for (int c = 0; c < 2; ++c) {
      const int o = ((c << 6) + rw) * LDT + k8;
      *(bf16x8*)(Gh + o) = vgh[c];
      *(bf16x8*)(Gl + o) = vgl[c];
      *(bf16x8*)(Uh + o) = vuh[c];
      *(bf16x8*)(Ul + o) = vul[c];
    }
    if (kt + 1 < NT) load_tile(kt + 1);  // next tile in flight across MFMA phase
    __syncthreads();  // LDS tile ready

#pragma unroll
    for (int ks = 0; ks < 2; ++ks) {
      const int kc = ks * 16 + (lane >> 5) * 8;
      const int ar = wm * 64 + (lane & 31);
      const int br = wn * 64 + (lane & 31);
      bf16x8 fah[2], fal[2];
#pragma unroll
      for (int fm = 0; fm < 2; ++fm) {
        fah[fm] = *(const bf16x8*)(Ah + (ar + fm * 32) * LDT + kc);
        fal[fm] = *(const bf16x8*)(Al + (ar + fm * 32) * LDT + kc);
      }
#pragma unroll
      for (int fn = 0; fn < 2; ++fn) {
        const int ro = (br + fn * 32) * LDT + kc;
        bf16x8 gh = *(const bf16x8*)(Gh + ro);
        bf16x8 gl = *(const bf16x8*)(Gl + ro);
        bf16x8 uh = *(const bf16x8*)(Uh + ro);
        bf16x8 ul = *(const bf16x8*)(Ul + ro);
#pragma unroll
        for (int fm = 0; fm < 2; ++fm) {
          accg[fm][fn] = __builtin_amdgcn_mfma_f32_32x32x16_bf16(fah[fm], gh, accg[fm][fn], 0, 0, 0);
          accg[fm][fn] = __builtin_amdgcn_mfma_f32_32x32x16_bf16(fah[fm], gl, accg[fm][fn], 0, 0, 0);
          accg[fm][fn] = __builtin_amdgcn_mfma_f32_32x32x16_bf16(fal[fm], gh, accg[fm][fn], 0, 0, 0);
          accu[fm][fn] = __builtin_amdgcn_mfma_f32_32x32x16_bf16(fah[fm], uh, accu[fm][fn], 0, 0, 0);
          accu[fm][fn] = __builtin_amdgcn_mfma_f32_32x32x16_bf16(fah[fm], ul, accu[fm][fn], 0, 0, 0);
          accu[fm][fn] = __builtin_amdgcn_mfma_f32_32x32x16_bf16(fal[fm], uh, accu[fm][fn], 0, 0, 0);
        }
      }
    }
  }

  // epilogue: h = silu(g)*u ; C/D map: col=lane&31, row=(j&3)+8*(j>>2)+4*(lane>>5)
  const int crb  = (lane >> 5) * 4;
  const int ccol = lane & 31;
#pragma unroll
  for (int fm = 0; fm < 2; ++fm)
#pragma unroll
    for (int fn = 0; fn < 2; ++fn)
#pragma unroll
      for (int j = 0; j < 16; ++j) {
        const int rl = wm * 64 + fm * 32 + (j & 3) + ((j >> 2) << 3) + crb;
        if (m0 + rl < nloc) {
          const float gv = accg[fm][fn][j];
          const float uv = accu[fm][fn][j];
          const float hv = gv / (1.f + __expf(-gv)) * uv;
          unsigned short hh, hl;
          split2(hv, hh, hl);
          const size_t idx = (size_t)(lo + m0 + rl) * HIDDEN + (n0 + wn * 64 + fn * 32 + ccol);
          g_h_hi[idx] = hh;
          g_h_lo[idx] = hl;
        }
      }
}

// ---------------- Stage 2: out = h @ D^T ----------------
__global__ __launch_bounds__(256, 2)
void moe_s2(const int* __restrict__ counts, float* __restrict__ out) {
  const int e = blockIdx.z;
  int lo, nloc;
  expert_range(counts, e, lo, nloc);
  const int m0 = blockIdx.x * BM;
  if (m0 >= nloc) return;
  const int n0 = blockIdx.y * BN;

  __shared__ unsigned short sm[4 * TILE];
  unsigned short* const Ah = sm;
  unsigned short* const Al = sm + TILE;
  unsigned short* const Bh = sm + 2 * TILE;
  unsigned short* const Bl = sm + 3 * TILE;

  const int tid  = threadIdx.x;
  const int lane = tid & 63;
  const int w    = tid >> 6;
  const int wm   = w >> 1, wn = w & 1;

  const unsigned short* const hhg = g_h_hi + (size_t)lo * HIDDEN;
  const unsigned short* const hlg = g_h_lo + (size_t)lo * HIDDEN;
  const size_t db = ((size_t)e * DIM + n0) * HIDDEN;
  const unsigned short* const Bhg = g_d_hi + db;
  const unsigned short* const Blg = g_d_lo + db;

  const int k8 = (tid & 3) * 8;
  const int rw = tid >> 2;

  f32x16 acc[2][2];
#pragma unroll
  for (int i = 0; i < 2; ++i)
#pragma unroll
    for (int j = 0; j < 2; ++j)
#pragma unroll
      for (int k = 0; k < 16; ++k) acc[i][j][k] = 0.f;

  bf16x8 vah[2], val[2], vbh[2], vbl[2];

  auto load_tile = [&](int kt) {
    const int kb = kt * BK + k8;
#pragma unroll
    for (int c = 0; c < 2; ++c) {
      const int r  = (c << 6) + rw;
      const int ra = (m0 + r < nloc) ? (m0 + r) : m0;
      vah[c] = *(const bf16x8*)(hhg + (size_t)ra * HIDDEN + kb);
      val[c] = *(const bf16x8*)(hlg + (size_t)ra * HIDDEN + kb);
      const size_t ro = (size_t)r * HIDDEN + kb;
      vbh[c] = *(const bf16x8*)(Bhg + ro);
      vbl[c] = *(const bf16x8*)(Blg + ro);
    }
  };

  const int NT = HIDDEN / BK;  // 32
  load_tile(0);

  for (int kt = 0; kt < NT; ++kt) {
    __syncthreads();
#pragma unroll
    for (int c = 0; c < 2; ++c) {
      const int o = ((c << 6) + rw) * LDT + k8;
      *(bf16x8*)(Ah + o) = vah[c];
      *(bf16x8*)(Al + o) = val[c];
      *(bf16x8*)(Bh + o) = vbh[c];
      *(bf16x8*)(Bl + o) = vbl[c];
    }
    if (kt + 1 < NT) load_tile(kt + 1);
    __syncthreads();

#pragma unroll
    for (int ks = 0; ks < 2; ++ks) {
      const int kc = ks * 16 + (lane >> 5) * 8;
      const int ar = wm * 64 + (lane & 31);
      const int br = wn * 64 + (lane & 31);
      bf16x8 fah[2], fal[2];
#pragma unroll
      for (int fm = 0; fm < 2; ++fm) {
        fah[fm] = *(const bf16x8*)(Ah + (ar + fm * 32) * LDT + kc);
        fal[fm] = *(const bf16x8*)(Al + (ar + fm * 32) * LDT + kc);
      }
#pragma unroll
      for (int fn = 0; fn < 2; ++fn) {
        const int ro = (br + fn * 32) * LDT + kc;
        bf16x8 bh = *(const bf16x8*)(Bh + ro);
        bf16x8 bl = *(const bf16x8*)(Bl + ro);
#pragma unroll
        for (int fm = 0; fm < 2; ++fm) {
          acc[fm][fn] = __builtin_amdgcn_mfma_f32_32x32x16_bf16(fah[fm], bh, acc[fm][fn], 0, 0, 0);
          acc[fm][fn] = __builtin_amdgcn_mfma_f32_32x32x16_bf16(fah[fm], bl, acc[fm][fn], 0, 0, 0);
          acc[fm][fn] = __builtin_amdgcn_mfma_f32_32x32x16_bf16(fal[fm], bh, acc[fm][fn], 0, 0, 0);
        }
      }
    }
  }

  const int crb  = (lane >> 5) * 4;
  const int ccol = lane & 31;
#pragma unroll
  for (int fm = 0; fm < 2; ++fm)
#pragma unroll
    for (int fn = 0; fn < 2; ++fn)
#pragma unroll
      for (int j = 0; j < 16; ++j) {
        const int rl = wm * 64 + fm * 32 + (j & 3) + ((j >> 2) << 3) + crb;
        if (m0 + rl < nloc) {
          out[(size_t)(lo + m0 + rl) * DIM + (n0 + wn * 64 + fn * 32 + ccol)] = acc[fm][fn][j];
        }
      }
}

extern "C" void kernel_launch(void* const* d_in, const int* in_sizes, int n_in,
                              void* d_out, int out_size, void* d_ws, size_t ws_size,
                              hipStream_t stream) {
  const float* x     = (const float*)d_in[0];
  const float* gate  = (const float*)d_in[1];
  const float* up    = (const float*)d_in[2];
  const float* down  = (const float*)d_in[3];
  const int*   cnts  = (const int*)d_in[4];
  float*       out   = (float*)d_out;
  (void)d_ws; (void)ws_size;  // unused: all scratch in static __device__ buffers

  unsigned short *gh, *gl, *uh, *ul, *dh, *dl;
  hipGetSymbolAddress((void**)&gh, HIP_SYMBOL(g_g_hi));
  hipGetSymbolAddress((void**)&gl, HIP_SYMBOL(g_g_lo));
  hipGetSymbolAddress((void**)&uh, HIP_SYMBOL(g_u_hi));
  hipGetSymbolAddress((void**)&ul, HIP_SYMBOL(g_u_lo));
  hipGetSymbolAddress((void**)&dh, HIP_SYMBOL(g_d_hi));
  hipGetSymbolAddress((void**)&dl, HIP_SYMBOL(g_d_lo));

  const int n4 = (int)(W_ELEMS / 4);
  dim3 blk(256, 1, 1);
  split_planes<<<2048, blk, 0, stream>>>(gate, gh, gl, n4);
  split_planes<<<2048, blk, 0, stream>>>(up,   uh, ul, n4);
  split_planes<<<2048, blk, 0, stream>>>(down, dh, dl, n4);
  moe_s1<<<dim3(TOTAL / BM, HIDDEN / BN, NE), blk, 0, stream>>>(x, cnts);
  moe_s2<<<dim3(TOTAL / BM, DIM / BN, NE), blk, 0, stream>>>(cnts, out);
}